// Round 3
// baseline (132.957 us; speedup 1.0000x reference)
//
#include <hip/hip_runtime.h>
#include <math.h>

#define NN 512
#define MM 100

typedef float f32x4 __attribute__((ext_vector_type(4)));

// ws layout (floats):
//  St   [NN*MM]   sin table: St[x*MM + j] = sin(pi * x/(NN-1) * (j+1))
//  B_u  [MM*NN]   transposed: B_u[j*NN + x]
//  B_v  [MM*NN]
//  dx   [NN*NN]
//  dy   [NN*NN]

__global__ void sin_table_kernel(float* __restrict__ St) {
    int tid = blockIdx.x * blockDim.x + threadIdx.x;
    if (tid >= NN * MM) return;
    int x = tid / MM, j = tid % MM;
    double arg = M_PI * ((double)x / (double)(NN - 1)) * (double)(j + 1);
    St[tid] = (float)sin(arg);
}

__global__ void bcoef_kernel(const float* __restrict__ St,
                             const float* __restrict__ c_u,
                             const float* __restrict__ c_v,
                             float* __restrict__ B_u,
                             float* __restrict__ B_v) {
    int x = blockIdx.x;      // [0, NN)
    int j = threadIdx.x;     // [0, MM)
    if (j >= MM) return;
    float au = 0.f, av = 0.f;
    for (int i = 0; i < MM; ++i) {
        int i1 = i + 1, j1 = j + 1;
        int r2i = i1 * i1 + j1 * j1;
        float w = (r2i <= 10100) ? (1.0f / sqrtf((float)r2i)) : 0.0f;
        float sw = St[x * MM + i] * w;
        au += sw * c_u[i * MM + j];
        av += sw * c_v[i * MM + j];
    }
    B_u[j * NN + x] = au;   // transposed store -> coalesced reads later
    B_v[j * NN + x] = av;
}

__global__ void field_kernel(const float* __restrict__ St,
                             const float* __restrict__ B_u,
                             const float* __restrict__ B_v,
                             float scale,
                             float* __restrict__ dx,
                             float* __restrict__ dy) {
    int tid = blockIdx.x * blockDim.x + threadIdx.x;   // y*NN + x
    if (tid >= NN * NN) return;
    int y = tid / NN, x = tid % NN;
    float du = 0.f, dv = 0.f;
    #pragma unroll 4
    for (int j = 0; j < MM; ++j) {
        float s = St[y * MM + j];
        du += B_u[j * NN + x] * s;
        dv += B_v[j * NN + x] * s;
    }
    dx[tid] = scale * du;
    dy[tid] = scale * dv;
}

#define PLANES_PER_BLOCK 8
#define PX_PER_THREAD 4
#define TPB 256
// pixels per block = 1024 = 2 rows; blocks per plane-slab = 256

__global__ void remap_kernel(const float* __restrict__ img,
                             const float* __restrict__ dx,
                             const float* __restrict__ dy,
                             float* __restrict__ out,
                             int planes) {
    // --- XCD-bijective swizzle: contiguous sid -> contiguous rows/plane-groups
    // per XCD, so each input row is L2-resident on exactly one XCD.
    int nb = gridDim.x;
    int bid = blockIdx.x;
    int q = nb >> 3, r = nb & 7;
    int xcd = bid & 7;
    int i = bid >> 3;
    int sid = (xcd < r ? xcd * (q + 1) : r * (q + 1) + (xcd - r) * q) + i;

    int pg  = sid >> 8;        // plane-group (each slab = 256 blocks)
    int blk = sid & 255;       // block within plane slab

    int base_pix = blk * (TPB * PX_PER_THREAD) + threadIdx.x * PX_PER_THREAD;
    int y = base_pix >> 9;     // /512
    int x = base_pix & 511;

    f32x4 dxv = *reinterpret_cast<const f32x4*>(dx + base_pix);
    f32x4 dyv = *reinterpret_cast<const f32x4*>(dy + base_pix);

    int   idx00[4], idx01[4], idx10[4], idx11[4];
    float w00[4], w01[4], w10[4], w11[4];

    #pragma unroll
    for (int k = 0; k < PX_PER_THREAD; ++k) {
        float xn = fminf(fmaxf((float)(x + k) - dxv[k], 0.0f), (float)(NN - 1));
        float yn = fminf(fmaxf((float)y       - dyv[k], 0.0f), (float)(NN - 1));
        int xf = (int)floorf(xn), yf = (int)floorf(yn);
        int xc = (int)ceilf(xn),  yc = (int)ceilf(yn);
        float xv = xn - (float)xf, yv = yn - (float)yf;
        w00[k] = (1.f - yv) * (1.f - xv);
        w01[k] = (1.f - yv) * xv;
        w10[k] = yv * (1.f - xv);
        w11[k] = yv * xv;
        idx00[k] = yf * NN + xf;  idx01[k] = yf * NN + xc;
        idx10[k] = yc * NN + xf;  idx11[k] = yc * NN + xc;
    }

    int p0 = pg * PLANES_PER_BLOCK;
    int p1 = p0 + PLANES_PER_BLOCK; if (p1 > planes) p1 = planes;
    for (int p = p0; p < p1; ++p) {
        const float* __restrict__ ip = img + (size_t)p * (NN * NN);
        f32x4 o;
        #pragma unroll
        for (int k = 0; k < PX_PER_THREAD; ++k) {
            o[k] = w00[k] * ip[idx00[k]] + w01[k] * ip[idx01[k]]
                 + w10[k] * ip[idx10[k]] + w11[k] * ip[idx11[k]];
        }
        // output is never re-read: bypass L2 so img rows stay resident
        __builtin_nontemporal_store(o,
            reinterpret_cast<f32x4*>(out + (size_t)p * (NN * NN) + base_pix));
    }
}

extern "C" void kernel_launch(void* const* d_in, const int* in_sizes, int n_in,
                              void* d_out, int out_size, void* d_ws, size_t ws_size,
                              hipStream_t stream) {
    const float* img = (const float*)d_in[0];
    const float* c_u = (const float*)d_in[1];
    const float* c_v = (const float*)d_in[2];
    float* out = (float*)d_out;

    int planes = in_sizes[0] / (NN * NN);   // 96

    float* ws  = (float*)d_ws;
    float* St  = ws;
    float* B_u = St  + NN * MM;
    float* B_v = B_u + MM * NN;
    float* dx  = B_v + MM * NN;
    float* dy  = dx  + NN * NN;

    double log_cut = log((double)MM + 1e-6);
    double T1 = 1.0 / (M_PI * (double)NN * (double)NN * log_cut);
    double T2 = 4.0 / (M_PI * M_PI * M_PI * (double)MM * (double)MM * log_cut);
    if (T2 < T1) T2 = T1;
    double T = 0.5 * (T1 + T2);
    float scale = (float)(sqrt(T) * (double)NN);

    sin_table_kernel<<<(NN * MM + 255) / 256, 256, 0, stream>>>(St);
    bcoef_kernel<<<NN, 128, 0, stream>>>(St, c_u, c_v, B_u, B_v);
    field_kernel<<<(NN * NN + 255) / 256, 256, 0, stream>>>(St, B_u, B_v, scale, dx, dy);

    int blocks_per_slab = (NN * NN) / (TPB * PX_PER_THREAD);       // 256
    int groups = (planes + PLANES_PER_BLOCK - 1) / PLANES_PER_BLOCK; // 12
    remap_kernel<<<blocks_per_slab * groups, TPB, 0, stream>>>(img, dx, dy, out, planes);
}

// Round 4
// 97.558 us; speedup vs baseline: 1.3628x; 1.3628x over previous
//
#include <hip/hip_runtime.h>
#include <math.h>

#define NN 512
#define MM 100

// ws layout (floats):
//  St   [NN*MM]   sin table: St[x*MM + j] = sin(pi * x/(NN-1) * (j+1))
//  B_u  [MM*NN]   transposed: B_u[j*NN + x]
//  B_v  [MM*NN]
//  dx   [NN*NN]
//  dy   [NN*NN]

__global__ void sin_table_kernel(float* __restrict__ St) {
    int tid = blockIdx.x * blockDim.x + threadIdx.x;
    if (tid >= NN * MM) return;
    int x = tid / MM, j = tid % MM;
    double arg = M_PI * ((double)x / (double)(NN - 1)) * (double)(j + 1);
    St[tid] = (float)sin(arg);
}

__global__ void bcoef_kernel(const float* __restrict__ St,
                             const float* __restrict__ c_u,
                             const float* __restrict__ c_v,
                             float* __restrict__ B_u,
                             float* __restrict__ B_v) {
    int x = blockIdx.x;      // [0, NN)
    int j = threadIdx.x;     // [0, MM)
    if (j >= MM) return;
    float au = 0.f, av = 0.f;
    for (int i = 0; i < MM; ++i) {
        int i1 = i + 1, j1 = j + 1;
        int r2i = i1 * i1 + j1 * j1;
        float w = (r2i <= 10100) ? (1.0f / sqrtf((float)r2i)) : 0.0f;
        float sw = St[x * MM + i] * w;
        au += sw * c_u[i * MM + j];
        av += sw * c_v[i * MM + j];
    }
    B_u[j * NN + x] = au;   // transposed store -> coalesced reads later
    B_v[j * NN + x] = av;
}

__global__ void field_kernel(const float* __restrict__ St,
                             const float* __restrict__ B_u,
                             const float* __restrict__ B_v,
                             float scale,
                             float* __restrict__ dx,
                             float* __restrict__ dy) {
    int tid = blockIdx.x * blockDim.x + threadIdx.x;   // y*NN + x
    if (tid >= NN * NN) return;
    int y = tid / NN, x = tid % NN;
    float du = 0.f, dv = 0.f;
    #pragma unroll 4
    for (int j = 0; j < MM; ++j) {
        float s = St[y * MM + j];
        du += B_u[j * NN + x] * s;
        dv += B_v[j * NN + x] * s;
    }
    dx[tid] = scale * du;
    dy[tid] = scale * dv;
}

#define PLANES_PER_BLOCK 8
#define TPB 256
// 1 px/thread: lane-stride-1 gathers -> ~4-5 cache lines per wave gather
// (PX=4 variant quadrupled TA line-transactions and regressed; see R3)

__global__ void remap_kernel(const float* __restrict__ img,
                             const float* __restrict__ dx,
                             const float* __restrict__ dy,
                             float* __restrict__ out,
                             int planes) {
    // XCD-bijective swizzle (nb % 8 == 0): each XCD owns a contiguous sid
    // range -> contiguous output rows per plane-group -> input rows are
    // L2-resident on exactly one XCD. Confirmed: FETCH 182 MB -> 61.5 MB.
    int nb = gridDim.x;
    int bid = blockIdx.x;
    int sid = (bid & 7) * (nb >> 3) + (bid >> 3);

    int pg  = sid >> 10;        // plane-group (1024 blocks per plane slab)
    int blk = sid & 1023;

    int pix = blk * TPB + threadIdx.x;   // y*NN + x within a plane
    int y = pix >> 9;
    int x = pix & 511;

    float xn = fminf(fmaxf((float)x - dx[pix], 0.0f), (float)(NN - 1));
    float yn = fminf(fmaxf((float)y - dy[pix], 0.0f), (float)(NN - 1));

    int xf = (int)floorf(xn), yf = (int)floorf(yn);
    int xc = (int)ceilf(xn),  yc = (int)ceilf(yn);
    float xv = xn - (float)xf, yv = yn - (float)yf;

    float w00 = (1.f - yv) * (1.f - xv);
    float w01 = (1.f - yv) * xv;
    float w10 = yv * (1.f - xv);
    float w11 = yv * xv;

    int i00 = yf * NN + xf, i01 = yf * NN + xc;
    int i10 = yc * NN + xf, i11 = yc * NN + xc;

    int p0 = pg * PLANES_PER_BLOCK;
    int p1 = p0 + PLANES_PER_BLOCK; if (p1 > planes) p1 = planes;
    for (int p = p0; p < p1; ++p) {
        const float* __restrict__ ip = img + (size_t)p * (NN * NN);
        float o = w00 * ip[i00] + w01 * ip[i01]
                + w10 * ip[i10] + w11 * ip[i11];
        // output never re-read: bypass L2 so img rows stay resident
        __builtin_nontemporal_store(o, out + (size_t)p * (NN * NN) + pix);
    }
}

extern "C" void kernel_launch(void* const* d_in, const int* in_sizes, int n_in,
                              void* d_out, int out_size, void* d_ws, size_t ws_size,
                              hipStream_t stream) {
    const float* img = (const float*)d_in[0];
    const float* c_u = (const float*)d_in[1];
    const float* c_v = (const float*)d_in[2];
    float* out = (float*)d_out;

    int planes = in_sizes[0] / (NN * NN);   // 96

    float* ws  = (float*)d_ws;
    float* St  = ws;
    float* B_u = St  + NN * MM;
    float* B_v = B_u + MM * NN;
    float* dx  = B_v + MM * NN;
    float* dy  = dx  + NN * NN;

    double log_cut = log((double)MM + 1e-6);
    double T1 = 1.0 / (M_PI * (double)NN * (double)NN * log_cut);
    double T2 = 4.0 / (M_PI * M_PI * M_PI * (double)MM * (double)MM * log_cut);
    if (T2 < T1) T2 = T1;
    double T = 0.5 * (T1 + T2);
    float scale = (float)(sqrt(T) * (double)NN);

    sin_table_kernel<<<(NN * MM + 255) / 256, 256, 0, stream>>>(St);
    bcoef_kernel<<<NN, 128, 0, stream>>>(St, c_u, c_v, B_u, B_v);
    field_kernel<<<(NN * NN + 255) / 256, 256, 0, stream>>>(St, B_u, B_v, scale, dx, dy);

    int blocks_per_slab = (NN * NN) / TPB;                           // 1024
    int groups = (planes + PLANES_PER_BLOCK - 1) / PLANES_PER_BLOCK; // 12
    remap_kernel<<<blocks_per_slab * groups, TPB, 0, stream>>>(img, dx, dy, out, planes);
}

// Round 5
// 85.657 us; speedup vs baseline: 1.5522x; 1.1389x over previous
//
#include <hip/hip_runtime.h>
#include <math.h>

#define NN 512
#define MM 100
#define TPB 256
#define ROWS_OUT 8            // output rows per block strip
#define ROWS_LDS 24           // staged input-row window (covers |dy| <= ~7.5)
#define PLANES_PER_BLOCK 8
#define PXPT 16               // px per thread per plane = ROWS_OUT*NN/TPB

typedef float f32x4 __attribute__((ext_vector_type(4)));

// ws layout (floats): St[NN*MM] | B_u[MM*NN] | B_v[MM*NN] | dx[NN*NN] | dy[NN*NN]

__global__ void sin_table_kernel(float* __restrict__ St) {
    int tid = blockIdx.x * blockDim.x + threadIdx.x;
    if (tid >= NN * MM) return;
    int x = tid / MM, j = tid % MM;
    double arg = M_PI * ((double)x / (double)(NN - 1)) * (double)(j + 1);
    St[tid] = (float)sin(arg);
}

__global__ void bcoef_kernel(const float* __restrict__ St,
                             const float* __restrict__ c_u,
                             const float* __restrict__ c_v,
                             float* __restrict__ B_u,
                             float* __restrict__ B_v) {
    int x = blockIdx.x;
    int j = threadIdx.x;
    if (j >= MM) return;
    float au = 0.f, av = 0.f;
    for (int i = 0; i < MM; ++i) {
        int i1 = i + 1, j1 = j + 1;
        int r2i = i1 * i1 + j1 * j1;
        float w = (r2i <= 10100) ? (1.0f / sqrtf((float)r2i)) : 0.0f;
        float sw = St[x * MM + i] * w;
        au += sw * c_u[i * MM + j];
        av += sw * c_v[i * MM + j];
    }
    B_u[j * NN + x] = au;
    B_v[j * NN + x] = av;
}

__global__ void field_kernel(const float* __restrict__ St,
                             const float* __restrict__ B_u,
                             const float* __restrict__ B_v,
                             float scale,
                             float* __restrict__ dx,
                             float* __restrict__ dy) {
    int tid = blockIdx.x * blockDim.x + threadIdx.x;
    if (tid >= NN * NN) return;
    int y = tid / NN, x = tid % NN;
    float du = 0.f, dv = 0.f;
    #pragma unroll 4
    for (int j = 0; j < MM; ++j) {
        float s = St[y * MM + j];
        du += B_u[j * NN + x] * s;
        dv += B_v[j * NN + x] * s;
    }
    dx[tid] = scale * du;
    dy[tid] = scale * dv;
}

__global__ __launch_bounds__(TPB, 3)
void remap_kernel(const float* __restrict__ img,
                  const float* __restrict__ dx,
                  const float* __restrict__ dy,
                  float* __restrict__ out,
                  int planes) {
    __shared__ __align__(16) float rows[ROWS_LDS * NN + 2];  // +2 pad (zeroed)
    __shared__ int s_mn[4], s_mx[4];
    __shared__ int s_r0, s_nr;

    // XCD-bijective swizzle (gridDim.x % 8 == 0): each XCD owns contiguous
    // sids -> contiguous row-strips -> staged rows L2-resident on one XCD.
    int nb = gridDim.x;
    int bid = blockIdx.x;
    int sid = (bid & 7) * (nb >> 3) + (bid >> 3);
    int strip = sid & 63;        // 64 strips per plane (512/8)
    int pg    = sid >> 6;        // plane group

    int t = threadIdx.x;
    int Y = strip * ROWS_OUT;

    // --- per-pixel precompute (once; reused for 8 planes) ---
    float w00[PXPT], w01[PXPT], w10[PXPT], w11[PXPT];
    int offA[PXPT], offB[PXPT];   // absolute dword offsets within a plane
    int myf = NN, Myc = -1;
    #pragma unroll
    for (int i = 0; i < PXPT; ++i) {
        int xi = ((i & 1) << 8) + t;
        int yi = Y + (i >> 1);
        int pix = (yi << 9) + xi;
        float xn = fminf(fmaxf((float)xi - dx[pix], 0.0f), (float)(NN - 1));
        float yn = fminf(fmaxf((float)yi - dy[pix], 0.0f), (float)(NN - 1));
        int xf = (int)floorf(xn), yf = (int)floorf(yn);
        int yc = (int)ceilf(yn);
        float xv = xn - (float)xf, yv = yn - (float)yf;
        w00[i] = (1.f - yv) * (1.f - xv);
        w01[i] = (1.f - yv) * xv;
        w10[i] = yv * (1.f - xv);
        w11[i] = yv * xv;
        offA[i] = (yf << 9) + xf;
        offB[i] = (yc << 9) + xf;
        myf = min(myf, yf);
        Myc = max(Myc, yc);
    }

    // block min/max of needed input rows
    for (int d = 32; d; d >>= 1) {
        myf = min(myf, __shfl_xor(myf, d));
        Myc = max(Myc, __shfl_xor(Myc, d));
    }
    int wid = t >> 6;
    if ((t & 63) == 0) { s_mn[wid] = myf; s_mx[wid] = Myc; }
    if (t < 2) rows[ROWS_LDS * NN + t] = 0.f;   // zero pad (weight-0 reads)
    __syncthreads();
    if (t == 0) {
        int a = min(min(s_mn[0], s_mn[1]), min(s_mn[2], s_mn[3]));
        int b = max(max(s_mx[0], s_mx[1]), max(s_mx[2], s_mx[3]));
        s_r0 = a; s_nr = b - a + 1;
    }
    __syncthreads();
    int r0 = s_r0, nr = s_nr;

    int p0 = pg * PLANES_PER_BLOCK;
    int p1 = p0 + PLANES_PER_BLOCK; if (p1 > planes) p1 = planes;

    if (nr <= ROWS_LDS) {
        // rebase offsets to the LDS window
        int rb = r0 << 9;
        #pragma unroll
        for (int i = 0; i < PXPT; ++i) { offA[i] -= rb; offB[i] -= rb; }

        int nbytes = nr << 11;   // nr * 512 * 4
        for (int p = p0; p < p1; ++p) {
            const char* ip = (const char*)(img + (size_t)p * (NN * NN) + rb);
            // coalesced float4 staging of the row window
            for (int off = t * 16; off < nbytes; off += TPB * 16) {
                *(f32x4*)((char*)rows + off) = *(const f32x4*)(ip + off);
            }
            __syncthreads();
            float* op = out + (size_t)p * (NN * NN);
            #pragma unroll
            for (int i = 0; i < PXPT; ++i) {
                float a0 = rows[offA[i]];
                float a1 = rows[offA[i] + 1];   // pad/next-row when xf=511 (w01=0)
                float b0 = rows[offB[i]];
                float b1 = rows[offB[i] + 1];
                float o = w00[i] * a0 + w01[i] * a1 + w10[i] * b0 + w11[i] * b1;
                int xi = ((i & 1) << 8) + t;
                int yi = Y + (i >> 1);
                __builtin_nontemporal_store(o, op + (yi << 9) + xi);
            }
            __syncthreads();   // before next plane's staging overwrites
        }
    } else {
        // fallback (only if a strip's |dy| range exceeds the LDS window):
        // direct global gathers, exact same math
        for (int p = p0; p < p1; ++p) {
            const float* __restrict__ ip = img + (size_t)p * (NN * NN);
            float* op = out + (size_t)p * (NN * NN);
            #pragma unroll
            for (int i = 0; i < PXPT; ++i) {
                int e1 = ((offA[i] & 511) == 511) ? 0 : 1;  // avoid OOB at x=511
                float a0 = ip[offA[i]], a1 = ip[offA[i] + e1];
                float b0 = ip[offB[i]], b1 = ip[offB[i] + e1];
                float o = w00[i] * a0 + w01[i] * a1 + w10[i] * b0 + w11[i] * b1;
                int xi = ((i & 1) << 8) + t;
                int yi = Y + (i >> 1);
                __builtin_nontemporal_store(o, op + (yi << 9) + xi);
            }
        }
    }
}

extern "C" void kernel_launch(void* const* d_in, const int* in_sizes, int n_in,
                              void* d_out, int out_size, void* d_ws, size_t ws_size,
                              hipStream_t stream) {
    const float* img = (const float*)d_in[0];
    const float* c_u = (const float*)d_in[1];
    const float* c_v = (const float*)d_in[2];
    float* out = (float*)d_out;

    int planes = in_sizes[0] / (NN * NN);   // 96

    float* ws  = (float*)d_ws;
    float* St  = ws;
    float* B_u = St  + NN * MM;
    float* B_v = B_u + MM * NN;
    float* dx  = B_v + MM * NN;
    float* dy  = dx  + NN * NN;

    double log_cut = log((double)MM + 1e-6);
    double T1 = 1.0 / (M_PI * (double)NN * (double)NN * log_cut);
    double T2 = 4.0 / (M_PI * M_PI * M_PI * (double)MM * (double)MM * log_cut);
    if (T2 < T1) T2 = T1;
    double T = 0.5 * (T1 + T2);
    float scale = (float)(sqrt(T) * (double)NN);

    sin_table_kernel<<<(NN * MM + 255) / 256, 256, 0, stream>>>(St);
    bcoef_kernel<<<NN, 128, 0, stream>>>(St, c_u, c_v, B_u, B_v);
    field_kernel<<<(NN * NN + 255) / 256, 256, 0, stream>>>(St, B_u, B_v, scale, dx, dy);

    int strips = NN / ROWS_OUT;                                      // 64
    int groups = (planes + PLANES_PER_BLOCK - 1) / PLANES_PER_BLOCK; // 12
    remap_kernel<<<strips * groups, TPB, 0, stream>>>(img, dx, dy, out, planes);
}

// Round 6
// 84.634 us; speedup vs baseline: 1.5710x; 1.0121x over previous
//
#include <hip/hip_runtime.h>
#include <math.h>

#define NN 512
#define MM 100
#define TPB 256
#define ROWS_OUT 4            // output rows per block strip
#define ROWS_LDS 13           // staged input-row window (4 + |dy|<=4.5 both sides)
#define PLANES_PER_BLOCK 8
#define PXPT 8                // px per thread per plane = ROWS_OUT*NN/TPB

typedef float f32x4 __attribute__((ext_vector_type(4)));

// ws layout (floats): St[NN*MM] | B_u[MM*NN] | B_v[MM*NN] | dx[NN*NN] | dy[NN*NN]

__global__ void sin_table_kernel(float* __restrict__ St) {
    int tid = blockIdx.x * blockDim.x + threadIdx.x;
    if (tid >= NN * MM) return;
    int x = tid / MM, j = tid % MM;
    double arg = M_PI * ((double)x / (double)(NN - 1)) * (double)(j + 1);
    St[tid] = (float)sin(arg);
}

__global__ void bcoef_kernel(const float* __restrict__ St,
                             const float* __restrict__ c_u,
                             const float* __restrict__ c_v,
                             float* __restrict__ B_u,
                             float* __restrict__ B_v) {
    int x = blockIdx.x;
    int j = threadIdx.x;
    if (j >= MM) return;
    float au = 0.f, av = 0.f;
    for (int i = 0; i < MM; ++i) {
        int i1 = i + 1, j1 = j + 1;
        int r2i = i1 * i1 + j1 * j1;
        float w = (r2i <= 10100) ? (1.0f / sqrtf((float)r2i)) : 0.0f;
        float sw = St[x * MM + i] * w;
        au += sw * c_u[i * MM + j];
        av += sw * c_v[i * MM + j];
    }
    B_u[j * NN + x] = au;
    B_v[j * NN + x] = av;
}

__global__ void field_kernel(const float* __restrict__ St,
                             const float* __restrict__ B_u,
                             const float* __restrict__ B_v,
                             float scale,
                             float* __restrict__ dx,
                             float* __restrict__ dy) {
    int tid = blockIdx.x * blockDim.x + threadIdx.x;
    if (tid >= NN * NN) return;
    int y = tid / NN, x = tid % NN;
    float du = 0.f, dv = 0.f;
    #pragma unroll 4
    for (int j = 0; j < MM; ++j) {
        float s = St[y * MM + j];
        du += B_u[j * NN + x] * s;
        dv += B_v[j * NN + x] * s;
    }
    dx[tid] = scale * du;
    dy[tid] = scale * dv;
}

__global__ __launch_bounds__(TPB, 6)
void remap_kernel(const float* __restrict__ img,
                  const float* __restrict__ dx,
                  const float* __restrict__ dy,
                  float* __restrict__ out,
                  int planes) {
    // 13*512+1 floats = 26628 B -> 6 blocks/CU (24 waves/CU, 75% occupancy)
    __shared__ __align__(16) float rows[ROWS_LDS * NN + 1];
    __shared__ int s_mn[4], s_mx[4];
    __shared__ int s_r0, s_nr;

    // XCD-bijective swizzle (gridDim.x % 8 == 0): adjacent strips (which share
    // halo rows) land on the same XCD, co-resident. Confirmed FETCH 182->61 MB.
    int nb = gridDim.x;
    int bid = blockIdx.x;
    int sid = (bid & 7) * (nb >> 3) + (bid >> 3);
    int strip = sid & 127;       // 128 strips per plane (512/4)
    int pg    = sid >> 7;        // plane group

    int t = threadIdx.x;
    int Y = strip * ROWS_OUT;

    // --- per-pixel precompute (once; reused across 8 planes) ---
    float w00[PXPT], w01[PXPT], w10[PXPT], w11[PXPT];
    int offA[PXPT], offB[PXPT];   // absolute dword offsets within a plane
    int myf = NN, Myc = -1;
    #pragma unroll
    for (int i = 0; i < PXPT; ++i) {
        int xi = ((i & 1) << 8) + t;
        int yi = Y + (i >> 1);
        int pix = (yi << 9) + xi;
        float xn = fminf(fmaxf((float)xi - dx[pix], 0.0f), (float)(NN - 1));
        float yn = fminf(fmaxf((float)yi - dy[pix], 0.0f), (float)(NN - 1));
        int xf = (int)floorf(xn), yf = (int)floorf(yn);
        int yc = (int)ceilf(yn);
        float xv = xn - (float)xf, yv = yn - (float)yf;
        w00[i] = (1.f - yv) * (1.f - xv);
        w01[i] = (1.f - yv) * xv;
        w10[i] = yv * (1.f - xv);
        w11[i] = yv * xv;
        offA[i] = (yf << 9) + xf;
        offB[i] = (yc << 9) + xf;
        myf = min(myf, yf);
        Myc = max(Myc, yc);
    }

    // block min/max of needed input rows
    for (int d = 32; d; d >>= 1) {
        myf = min(myf, __shfl_xor(myf, d));
        Myc = max(Myc, __shfl_xor(Myc, d));
    }
    int wid = t >> 6;
    if ((t & 63) == 0) { s_mn[wid] = myf; s_mx[wid] = Myc; }
    __syncthreads();
    if (t == 0) {
        int a = min(min(s_mn[0], s_mn[1]), min(s_mn[2], s_mn[3]));
        int b = max(max(s_mx[0], s_mx[1]), max(s_mx[2], s_mx[3]));
        s_r0 = a; s_nr = b - a + 1;
        // zero the single pad slot (read only with weight exactly 0:
        // xf==511 -> xv=0 -> w01=w11=0); keeps 0*garbage from being 0*NaN
        rows[(b - a + 1) * NN] = 0.f;
    }
    __syncthreads();
    int r0 = s_r0, nr = s_nr;

    int p0 = pg * PLANES_PER_BLOCK;
    int p1 = p0 + PLANES_PER_BLOCK; if (p1 > planes) p1 = planes;

    if (nr <= ROWS_LDS) {
        int rb = r0 << 9;
        #pragma unroll
        for (int i = 0; i < PXPT; ++i) { offA[i] -= rb; offB[i] -= rb; }

        int nbytes = nr << 11;   // nr * 512 * 4
        for (int p = p0; p < p1; ++p) {
            const char* ip = (const char*)(img + (size_t)p * (NN * NN) + rb);
            for (int off = t * 16; off < nbytes; off += TPB * 16) {
                *(f32x4*)((char*)rows + off) = *(const f32x4*)(ip + off);
            }
            __syncthreads();
            float* op = out + (size_t)p * (NN * NN);
            #pragma unroll
            for (int i = 0; i < PXPT; ++i) {
                float a0 = rows[offA[i]];
                float a1 = rows[offA[i] + 1];
                float b0 = rows[offB[i]];
                float b1 = rows[offB[i] + 1];
                float o = w00[i] * a0 + w01[i] * a1 + w10[i] * b0 + w11[i] * b1;
                int xi = ((i & 1) << 8) + t;
                int yi = Y + (i >> 1);
                __builtin_nontemporal_store(o, op + (yi << 9) + xi);
            }
            __syncthreads();
        }
    } else {
        // fallback: direct global gathers, same math (correct for any dy)
        for (int p = p0; p < p1; ++p) {
            const float* __restrict__ ip = img + (size_t)p * (NN * NN);
            float* op = out + (size_t)p * (NN * NN);
            #pragma unroll
            for (int i = 0; i < PXPT; ++i) {
                int e1 = ((offA[i] & 511) == 511) ? 0 : 1;
                float a0 = ip[offA[i]], a1 = ip[offA[i] + e1];
                float b0 = ip[offB[i]], b1 = ip[offB[i] + e1];
                float o = w00[i] * a0 + w01[i] * a1 + w10[i] * b0 + w11[i] * b1;
                int xi = ((i & 1) << 8) + t;
                int yi = Y + (i >> 1);
                __builtin_nontemporal_store(o, op + (yi << 9) + xi);
            }
        }
    }
}

extern "C" void kernel_launch(void* const* d_in, const int* in_sizes, int n_in,
                              void* d_out, int out_size, void* d_ws, size_t ws_size,
                              hipStream_t stream) {
    const float* img = (const float*)d_in[0];
    const float* c_u = (const float*)d_in[1];
    const float* c_v = (const float*)d_in[2];
    float* out = (float*)d_out;

    int planes = in_sizes[0] / (NN * NN);   // 96

    float* ws  = (float*)d_ws;
    float* St  = ws;
    float* B_u = St  + NN * MM;
    float* B_v = B_u + MM * NN;
    float* dx  = B_v + MM * NN;
    float* dy  = dx  + NN * NN;

    double log_cut = log((double)MM + 1e-6);
    double T1 = 1.0 / (M_PI * (double)NN * (double)NN * log_cut);
    double T2 = 4.0 / (M_PI * M_PI * M_PI * (double)MM * (double)MM * log_cut);
    if (T2 < T1) T2 = T1;
    double T = 0.5 * (T1 + T2);
    float scale = (float)(sqrt(T) * (double)NN);

    sin_table_kernel<<<(NN * MM + 255) / 256, 256, 0, stream>>>(St);
    bcoef_kernel<<<NN, 128, 0, stream>>>(St, c_u, c_v, B_u, B_v);
    field_kernel<<<(NN * NN + 255) / 256, 256, 0, stream>>>(St, B_u, B_v, scale, dx, dy);

    int strips = NN / ROWS_OUT;                                      // 128
    int groups = (planes + PLANES_PER_BLOCK - 1) / PLANES_PER_BLOCK; // 12
    remap_kernel<<<strips * groups, TPB, 0, stream>>>(img, dx, dy, out, planes);
}